// Round 14
// baseline (120.420 us; speedup 1.0000x reference)
//
#include <hip/hip_runtime.h>

typedef __attribute__((ext_vector_type(8)))  short bf16x8;
typedef __attribute__((ext_vector_type(4)))  short s16x4;
typedef __attribute__((ext_vector_type(4)))  float f32x4;
typedef __attribute__((ext_vector_type(16))) float f32x16;
typedef __attribute__((ext_vector_type(4)))  unsigned u32x4;
typedef __attribute__((ext_vector_type(4)))  _Float16 f16x4;

#define B_  2
#define S_  2048
#define H_  16
#define D_  64
#define E_  1024
#define M_  (B_*S_)
#define NH_ (M_*H_)
#define L2E 1.44269504f

__device__ __forceinline__ unsigned short f2bf(float f){
  unsigned x = __builtin_bit_cast(unsigned, f);
  x += 0x7fffu + ((x >> 16) & 1u);
  return (unsigned short)(x >> 16);
}
__device__ __forceinline__ unsigned pk_bf16(float lo, float hi){
  unsigned short a = __builtin_bit_cast(unsigned short, (__bf16)lo);
  unsigned short b = __builtin_bit_cast(unsigned short, (__bf16)hi);
  return (unsigned)a | ((unsigned)b << 16);
}

#define GLD16(gp, lp) __builtin_amdgcn_global_load_lds( \
    (const __attribute__((address_space(1))) unsigned*)(gp), \
    (__attribute__((address_space(3))) unsigned*)(lp), 16, 0, 0)

// ---------------- fused prep: x->bf16 + RoPE/mask tables | W^T bf16 ----------------
__global__ __launch_bounds__(256) void k_prep(const float* __restrict__ in, short* __restrict__ out,
                                              const float* __restrict__ mask,
                                              float* ct, float* st, float* maskC,
                                              const float* __restrict__ Wq, const float* __restrict__ Wk,
                                              const float* __restrict__ Wv, short* __restrict__ wt){
  const int bx = blockIdx.x;
  if(bx < 4096){
    int i = bx*256 + threadIdx.x;
    if(i < S_*32){                           // RoPE tables [2048][32]
      int s = i >> 5, f = i & 31;
      float invf = powf(10000.0f, -(float)f / 32.0f);
      float ph = (float)s * invf;
      ct[i] = cosf(ph);
      st[i] = sinf(ph);
      if(i < B_*S_) maskC[i] = fmaf(mask[i], L2E, -17.0f);   // log2-domain mask, -17 recenter
    }
    int j = i*4;
    float4 v = *(const float4*)(in + j);
    s16x4 o = { (short)f2bf(v.x), (short)f2bf(v.y), (short)f2bf(v.z), (short)f2bf(v.w) };
    *(s16x4*)(out + j) = o;
  } else {
    int w = bx - 4096;                       // 0..767
    int z = w >> 8, r = w & 255;
    const float* W = z==0 ? Wq : (z==1 ? Wk : Wv);
    short* outw = wt + (size_t)z*E_*E_;
    __shared__ short tile[64][72];
    int nb = (r & 15)*64, kb = (r >> 4)*64;
    int t = threadIdx.x;
    {
      int rr = t>>2, c0 = (t&3)*16;
      const float* src = W + (size_t)(kb+rr)*E_ + nb + c0;
      #pragma unroll
      for(int i=0;i<4;i++){
        float4 v = *(const float4*)(src + i*4);
        tile[rr][c0+i*4+0] = (short)f2bf(v.x);
        tile[rr][c0+i*4+1] = (short)f2bf(v.y);
        tile[rr][c0+i*4+2] = (short)f2bf(v.z);
        tile[rr][c0+i*4+3] = (short)f2bf(v.w);
      }
    }
    __syncthreads();
    {
      int n = t>>2, k0 = (t&3)*16;
      short* dst = outw + (size_t)(nb+n)*E_ + kb + k0;
      bf16x8 o0, o1;
      #pragma unroll
      for(int i=0;i<8;i++){ o0[i] = tile[k0+i][n]; o1[i] = tile[k0+8+i][n]; }
      *(bf16x8*)dst = o0;
      *(bf16x8*)(dst+8) = o1;
    }
  }
}

// ---------------- QKV GEMM + bias; BK=64 XOR-swizzled staging; RoPE / V^T epilogues ----------------
__global__ __launch_bounds__(256) void k_gemm(const short* __restrict__ A, const short* __restrict__ WT,
                                              const float* __restrict__ biasq, const float* __restrict__ biask,
                                              const float* __restrict__ biasv,
                                              short* __restrict__ oq, short* __restrict__ ok, short* __restrict__ ovt,
                                              const float* __restrict__ cost, const float* __restrict__ sint){
  const int z = blockIdx.z;
  const short* Bw = WT + (size_t)z*E_*E_;
  const float* bias = z==0 ? biasq : (z==1 ? biask : biasv);
  __shared__ short As[128*64];
  __shared__ short Bs[128*64];
  const int t = threadIdx.x, lane = t & 63, wid = t >> 6;
  const int mb = blockIdx.x*128, nb = blockIdx.y*128;
  const int wm = (wid>>1)*64, wn = (wid&1)*64;
  f32x4 acc[4][4] = {};
  for(int kt=0; kt<E_/64; kt++){
    __syncthreads();
    #pragma unroll
    for(int i=0;i<4;i++){
      int c = t + 256*i;
      int row = c>>3;
      int colg = ((c&7) ^ (row&7))*8;        // inverse-swizzled global column group
      GLD16(A  + (size_t)(mb + row)*E_ + kt*64 + colg, &As[c*8]);
      GLD16(Bw + (size_t)(nb + row)*E_ + kt*64 + colg, &Bs[c*8]);
    }
    __syncthreads();
    #pragma unroll
    for(int kk=0; kk<2; kk++){
      bf16x8 af[4], bfv[4];
      #pragma unroll
      for(int mf=0; mf<4; mf++){
        int r = wm + mf*16 + (lane&15);
        int c8 = (kk*4 + (lane>>4)) ^ (r&7); // swizzled read column
        af[mf] = *(const bf16x8*)&As[r*64 + c8*8];
      }
      #pragma unroll
      for(int nf=0; nf<4; nf++){
        int r = wn + nf*16 + (lane&15);
        int c8 = (kk*4 + (lane>>4)) ^ (r&7);
        bfv[nf] = *(const bf16x8*)&Bs[r*64 + c8*8];
      }
      #pragma unroll
      for(int mf=0; mf<4; mf++)
        #pragma unroll
        for(int nf=0; nf<4; nf++)
          acc[mf][nf] = __builtin_amdgcn_mfma_f32_16x16x32_bf16(af[mf], bfv[nf], acc[mf][nf], 0, 0, 0);
    }
  }
  const int col16 = lane & 15, rg = lane >> 4;
  float bvs[4];
  #pragma unroll
  for(int nf=0; nf<4; nf++) bvs[nf] = bias[nb + wn + nf*16 + col16];
  if(z == 2){
    #pragma unroll
    for(int mf=0; mf<4; mf++){
      int row0 = mb + wm + mf*16 + rg*4;
      int bb2 = row0 >> 11, ss = row0 & (S_-1);
      #pragma unroll
      for(int nf=0; nf<4; nf++){
        int e = nb + wn + nf*16 + col16;
        int hh = e >> 6, dd = e & 63;
        s16x4 w = { (short)f2bf(acc[mf][nf][0]+bvs[nf]), (short)f2bf(acc[mf][nf][1]+bvs[nf]),
                    (short)f2bf(acc[mf][nf][2]+bvs[nf]), (short)f2bf(acc[mf][nf][3]+bvs[nf]) };
        *(s16x4*)(ovt + ((size_t)(bb2*H_+hh)*D_+dd)*S_ + ss) = w;
      }
    }
  } else {
    short* out = (z==0) ? oq : ok;
    const float qs = (z==0) ? (0.125f*L2E) : 1.0f;   // fold score scale + log2e into q
    #pragma unroll
    for(int mf=0; mf<4; mf++)
      #pragma unroll
      for(int r=0; r<4; r++){
        int row = mb + wm + mf*16 + rg*4 + r;
        int srow = row & (S_-1);
        const float* cb = cost + (size_t)srow*32;
        const float* sb = sint + (size_t)srow*32;
        #pragma unroll
        for(int nf=0; nf<2; nf++){
          int d = nf*16 + col16;
          float c = cb[d], sn = sb[d];
          float x0 = acc[mf][nf][r]   + bvs[nf];
          float x1 = acc[mf][nf+2][r] + bvs[nf+2];
          out[(size_t)row*E_ + nb + wn + nf*16 + col16]     = (short)f2bf((x0*c - x1*sn)*qs);
          out[(size_t)row*E_ + nb + wn + (nf+2)*16 + col16] = (short)f2bf((x1*c + x0*sn)*qs);
        }
      }
  }
}

// ================= shared attention body macros =================
#define ATTN_TILE_BODY(KS, VS, TTABS) \
    f32x16 s0 = {}, s1 = {}; \
    __builtin_amdgcn_s_setprio(1); \
    _Pragma("unroll") \
    for(int dk=0; dk<4; dk++){ \
      bf16x8 kf0 = *(const bf16x8*)&KS[(l31)*72 + dk*16 + hl*8]; \
      bf16x8 kf1 = *(const bf16x8*)&KS[(32+l31)*72 + dk*16 + hl*8]; \
      s0 = __builtin_amdgcn_mfma_f32_32x32x16_bf16(kf0, qf[dk], s0, 0,0,0); \
      s1 = __builtin_amdgcn_mfma_f32_32x32x16_bf16(kf1, qf[dk], s1, 0,0,0); \
    } \
    __builtin_amdgcn_s_setprio(0); \
    { \
      const float* mt = mrow + (TTABS)*64 + hl*4; \
      _Pragma("unroll") \
      for(int bb=0; bb<4; bb++){ \
        f32x4 mv0 = *(const f32x4*)(mt + bb*8); \
        f32x4 mv1 = *(const f32x4*)(mt + 32 + bb*8); \
        _Pragma("unroll") \
        for(int a=0; a<4; a++){ s0[bb*4+a] += mv0[a]; s1[bb*4+a] += mv1[a]; } \
      } \
    } \
    _Pragma("unroll") \
    for(int i=0;i<16;i++) s0[i] = __builtin_amdgcn_exp2f(s0[i]); \
    _Pragma("unroll") \
    for(int i=0;i<16;i++) s1[i] = __builtin_amdgcn_exp2f(s1[i]); \
    float la=0.f, lb=0.f, lc=0.f, ld=0.f; \
    _Pragma("unroll") \
    for(int i=0;i<4;i++){ \
      la += s0[i];   lb += s0[4+i];  lc += s0[8+i];  ld += s0[12+i]; \
      la += s1[i];   lb += s1[4+i];  lc += s1[8+i];  ld += s1[12+i]; \
    } \
    float ls = (la+lb)+(lc+ld); \
    ls += __shfl_xor(ls, 32); \
    l_run += ls; \
    unsigned w0a[8], w1a[8]; \
    _Pragma("unroll") \
    for(int c=0;c<8;c++){ \
      int base = (c&3)*4; \
      float p0 = (c & 4) ? s1[base+0] : s0[base+0]; \
      float p1 = (c & 4) ? s1[base+1] : s0[base+1]; \
      float p2 = (c & 4) ? s1[base+2] : s0[base+2]; \
      float p3 = (c & 4) ? s1[base+3] : s0[base+3]; \
      w0a[c] = pk_bf16(p0, p1); \
      w1a[c] = pk_bf16(p2, p3); \
    }

#define ATTN_PV_BODY(VS) \
    __builtin_amdgcn_s_setprio(1); \
    _Pragma("unroll") \
    for(int ksl=0; ksl<4; ksl++){ \
      unsigned a0 = w0a[2*ksl], b0 = w0a[2*ksl+1]; \
      unsigned a1 = w1a[2*ksl], b1 = w1a[2*ksl+1]; \
      asm("v_permlane32_swap_b32 %0, %1" : "+v"(a0), "+v"(b0)); \
      asm("v_permlane32_swap_b32 %0, %1" : "+v"(a1), "+v"(b1)); \
      u32x4 pw = { a0, a1, b0, b1 }; \
      bf16x8 pf = __builtin_bit_cast(bf16x8, pw); \
      bf16x8 vf0 = *(const bf16x8*)&VS[(l31)*72 + ksl*16 + hl*8]; \
      bf16x8 vf1 = *(const bf16x8*)&VS[(32+l31)*72 + ksl*16 + hl*8]; \
      O0 = __builtin_amdgcn_mfma_f32_32x32x16_bf16(pf, vf0, O0, 0,0,0); \
      O1 = __builtin_amdgcn_mfma_f32_32x32x16_bf16(pf, vf1, O1, 0,0,0); \
    } \
    __builtin_amdgcn_s_setprio(0);

// ---------------- Flash attention ns=2, double-buffered (R8/R13-proven path) ----------------
__global__ __launch_bounds__(256,4) void k_attn(
    const short* __restrict__ qg, const short* __restrict__ kg,
    const short* __restrict__ vtg, const float* __restrict__ maskC,
    float* __restrict__ o0g, _Float16* __restrict__ o1g, float* __restrict__ lpart){
  __shared__ short Ks[2][64*72];
  __shared__ short Vs[2][64*72];
  const int flat = blockIdx.x;
  const int v = flat >> 3;
  const int bh = (flat & 7)*4 + (v >> 5);
  const int inner = v & 31;
  const int qb = inner >> 1, sp = inner & 1;
  const int h = bh & 15, b = bh >> 4;
  const int tid = threadIdx.x, wid = tid>>6, lane = tid&63;
  const int l31 = lane & 31, hl = lane >> 5;
  const int qw = qb*128 + wid*32;
  const int rr = tid>>3, ch = tid&7;
  const int kb0 = sp*16;
  const int NT = 16;

  bf16x8 qf[4];
  {
    const short* qp = qg + ((size_t)(b*S_ + qw + l31)*H_ + h)*D_;
    #pragma unroll
    for(int dk=0; dk<4; dk++)
      qf[dk] = *(const bf16x8*)(qp + dk*16 + hl*8);
  }
  f32x16 O0 = {}, O1 = {};
  float l_run = 0.f;
  const float* mrow = maskC + (size_t)b*S_;

  bf16x8 ka, kc, va, vc;
#define LOADT(kb) { \
    const short* ks_ = kg + ((size_t)(b*S_ + (kb)*64 + rr)*H_ + h)*D_ + ch*8; \
    ka = *(const bf16x8*)ks_;  kc = *(const bf16x8*)(ks_ + 32*H_*D_); \
    const short* vs_ = vtg + ((size_t)(b*H_ + h)*D_ + rr)*S_ + (kb)*64 + ch*8; \
    va = *(const bf16x8*)vs_;  vc = *(const bf16x8*)(vs_ + 32*S_); }
#define WRITET(pp) { \
    *(bf16x8*)&Ks[pp][rr*72 + ch*8]      = ka; \
    *(bf16x8*)&Ks[pp][(rr+32)*72 + ch*8] = kc; \
    *(bf16x8*)&Vs[pp][rr*72 + ch*8]      = va; \
    *(bf16x8*)&Vs[pp][(rr+32)*72 + ch*8] = vc; }

  LOADT(kb0);
  WRITET(0);
  LOADT(kb0+1);
  asm volatile("s_waitcnt lgkmcnt(0)" ::: "memory");
  __builtin_amdgcn_s_barrier();

  int p = 0;
  for(int tt=0; tt<NT; tt++){
    ATTN_TILE_BODY(Ks[p], Vs[p], kb0+tt)
    if(tt+1 < NT){
      WRITET(p^1);
      if(tt+2 < NT) LOADT(kb0+tt+2);
    }
    ATTN_PV_BODY(Vs[p])
    asm volatile("s_waitcnt lgkmcnt(0)" ::: "memory");
    __builtin_amdgcn_s_barrier();
    p ^= 1;
  }
#undef LOADT
#undef WRITET

  if(sp == 0){
    #pragma unroll
    for(int bb=0; bb<4; bb++)
      #pragma unroll
      for(int a=0; a<4; a++){
        int qrow = qw + a + 8*bb + 4*hl;
        float* op = o0g + ((size_t)(b*S_ + qrow)*H_ + h)*D_;
        op[l31]      = O0[bb*4+a];
        op[32 + l31] = O1[bb*4+a];
      }
  } else {
    #pragma unroll
    for(int bb=0; bb<4; bb++)
      #pragma unroll
      for(int a=0; a<4; a++){
        int qrow = qw + a + 8*bb + 4*hl;
        _Float16* op = o1g + ((size_t)(b*S_ + qrow)*H_ + h)*D_;
        op[l31]      = (_Float16)O0[bb*4+a];
        op[32 + l31] = (_Float16)O1[bb*4+a];
      }
  }
  if(lane < 32)
    lpart[(size_t)sp*NH_ + (size_t)(b*S_ + qw + l31)*H_ + h] = l_run;
}

// ---------------- Flash attention ns=3, single-buffer (18.4KB -> 6 blocks/CU, 24 waves/CU) ----------------
__global__ __launch_bounds__(256,4) void k_attn_s(
    const short* __restrict__ qg, const short* __restrict__ kg,
    const short* __restrict__ vtg, const float* __restrict__ maskC,
    float* __restrict__ o0g, _Float16* __restrict__ p1g, _Float16* __restrict__ p2g,
    float* __restrict__ lpart){
  __shared__ short Ks[64*72];   // single buffer: 9216B
  __shared__ short Vs[64*72];   // 9216B  -> total 18432B
  // grid 1536, XCD-clustered: flat&7=xcd, 192/xcd, 48 per bh (16 qb x 3 sp)
  const int flat = blockIdx.x;
  const int v = flat >> 3;
  const int bh = (flat & 7)*4 + v/48;
  const int inner = v % 48;
  const int qb = inner/3, sp = inner%3;
  const int h = bh & 15, b = bh >> 4;
  const int tid = threadIdx.x, wid = tid>>6, lane = tid&63;
  const int l31 = lane & 31, hl = lane >> 5;
  const int qw = qb*128 + wid*32;
  const int rr = tid>>3, ch = tid&7;
  const int kb0 = (sp*32)/3;                 // 0,10,21
  const int NT  = ((sp+1)*32)/3 - kb0;       // 10,11,11

  bf16x8 qf[4];
  {
    const short* qp = qg + ((size_t)(b*S_ + qw + l31)*H_ + h)*D_;
    #pragma unroll
    for(int dk=0; dk<4; dk++)
      qf[dk] = *(const bf16x8*)(qp + dk*16 + hl*8);
  }
  f32x16 O0 = {}, O1 = {};
  float l_run = 0.f;
  const float* mrow = maskC + (size_t)b*S_;

  bf16x8 ka, kc, va, vc;
#define LOADT(kb) { \
    const short* ks_ = kg + ((size_t)(b*S_ + (kb)*64 + rr)*H_ + h)*D_ + ch*8; \
    ka = *(const bf16x8*)ks_;  kc = *(const bf16x8*)(ks_ + 32*H_*D_); \
    const short* vs_ = vtg + ((size_t)(b*H_ + h)*D_ + rr)*S_ + (kb)*64 + ch*8; \
    va = *(const bf16x8*)vs_;  vc = *(const bf16x8*)(vs_ + 32*S_); }
#define WRITET() { \
    *(bf16x8*)&Ks[rr*72 + ch*8]      = ka; \
    *(bf16x8*)&Ks[(rr+32)*72 + ch*8] = kc; \
    *(bf16x8*)&Vs[rr*72 + ch*8]      = va; \
    *(bf16x8*)&Vs[(rr+32)*72 + ch*8] = vc; }

  LOADT(kb0);
  WRITET();
  __syncthreads();

  for(int tt=0; tt<NT; tt++){
    if(tt+1 < NT) LOADT(kb0+tt+1);   // issue early: body covers latency before the drain
    ATTN_TILE_BODY(Ks, Vs, kb0+tt)
    ATTN_PV_BODY(Vs)
    __syncthreads();                 // all waves done reading tile tt (drains vmcnt: loads arrived)
    if(tt+1 < NT){
      WRITET();                      // stage tile tt+1
      __syncthreads();               // writes visible before next QK
    }
  }
#undef LOADT
#undef WRITET

  if(sp == 0){
    #pragma unroll
    for(int bb=0; bb<4; bb++)
      #pragma unroll
      for(int a=0; a<4; a++){
        int qrow = qw + a + 8*bb + 4*hl;
        float* op = o0g + ((size_t)(b*S_ + qrow)*H_ + h)*D_;
        op[l31]      = O0[bb*4+a];
        op[32 + l31] = O1[bb*4+a];
      }
  } else {
    _Float16* pbuf = (sp == 1) ? p1g : p2g;
    #pragma unroll
    for(int bb=0; bb<4; bb++)
      #pragma unroll
      for(int a=0; a<4; a++){
        int qrow = qw + a + 8*bb + 4*hl;
        _Float16* op = pbuf + ((size_t)(b*S_ + qrow)*H_ + h)*D_;
        op[l31]      = (_Float16)O0[bb*4+a];
        op[32 + l31] = (_Float16)O1[bb*4+a];
      }
  }
  if(lane < 32)
    lpart[(size_t)sp*NH_ + (size_t)(b*S_ + qw + l31)*H_ + h] = l_run;
}

// ---------------- combine: out = (P0 + P1 [+ P2]) / (l0 + l1 [+ l2]) ----------------
__global__ __launch_bounds__(256) void k_comb(float* __restrict__ out, const _Float16* __restrict__ p1,
                                              const _Float16* __restrict__ p2,
                                              const float* __restrict__ lpart, int ns){
  int i = blockIdx.x*256 + threadIdx.x;
  int idx = i*4;
  int lidx = idx >> 6;                       // (b*S+q)*H + h
  float l = lpart[lidx] + lpart[NH_ + lidx];
  if(ns > 2) l += lpart[2*NH_ + lidx];
  float linv = 1.f / l;
  f32x4 a = *(f32x4*)(out + idx);
  f16x4 q1 = *(const f16x4*)(p1 + idx);
  f32x4 r;
  #pragma unroll
  for(int j=0;j<4;j++) r[j] = a[j] + (float)q1[j];
  if(ns > 2){
    f16x4 q2 = *(const f16x4*)(p2 + idx);
    #pragma unroll
    for(int j=0;j<4;j++) r[j] += (float)q2[j];
  }
  #pragma unroll
  for(int j=0;j<4;j++) r[j] *= linv;
  *(f32x4*)(out + idx) = r;
}

extern "C" void kernel_launch(void* const* d_in, const int* in_sizes, int n_in,
                              void* d_out, int out_size, void* d_ws, size_t ws_size,
                              hipStream_t stream){
  (void)in_sizes; (void)n_in; (void)out_size;
  const float* x    = (const float*)d_in[0];
  const float* mask = (const float*)d_in[1];
  const float* Wq   = (const float*)d_in[2];
  const float* bq   = (const float*)d_in[3];
  const float* Wk   = (const float*)d_in[4];
  const float* bk   = (const float*)d_in[5];
  const float* Wv   = (const float*)d_in[6];
  const float* bv   = (const float*)d_in[7];
  float* out = (float*)d_out;
  char* ws = (char*)d_ws;
  // ws map: [0,40M) proven; p2 @ [40M,48M) used only when ws_size >= 48M.
  float* cost  = (float*)(ws);                   // 256K
  float* sint  = (float*)(ws + (256u<<10));      // 256K
  float* maskC = (float*)(ws + (512u<<10));      // 16K
  float* lpart = (float*)(ws + (768u<<10));      // up to 768K (3 x NH f32), fits before 2M
  short* xb    = (short*)(ws + (2u<<20));        // 8M  x bf16 (aliased by f16 partial p1)
  short* wt    = (short*)(ws + (10u<<20));       // 6M  W^T bf16
  short* qb    = (short*)(ws + (16u<<20));       // 8M  q bf16
  short* kb    = (short*)(ws + (24u<<20));       // 8M  k bf16
  short* vtb   = (short*)(ws + (32u<<20));       // 8M  V^T bf16
  _Float16* p1 = (_Float16*)xb;                  // alias: xb dead after k_gemm
  _Float16* p2 = (_Float16*)(ws + (40u<<20));    // valid only if ws >= 48M

  const int ns = (ws_size >= (size_t)(48u<<20)) ? 3 : 2;   // deterministic per-deployment

  k_prep<<<dim3(4096+768), dim3(256), 0, stream>>>(x, xb, mask, cost, sint, maskC,
                                                   Wq, Wk, Wv, wt);
  k_gemm<<<dim3(32,8,3), dim3(256), 0, stream>>>(xb, wt, bq, bk, bv, qb, kb, vtb, cost, sint);
  if(ns == 2){
    k_attn<<<dim3(1024), dim3(256), 0, stream>>>(qb, kb, vtb, maskC, out, p1, lpart);
  } else {
    k_attn_s<<<dim3(1536), dim3(256), 0, stream>>>(qb, kb, vtb, maskC, out, p1, p2, lpart);
  }
  k_comb<<<dim3(4096), dim3(256), 0, stream>>>(out, p1, p2, lpart, ns);
}